// Round 7
// baseline (110.681 us; speedup 1.0000x reference)
//
#include <hip/hip_runtime.h>

#define NP 128      // proposals
#define NB 16       // neighbors per proposal
#define KK 64       // knn per node
#define LL 1024     // NB*KK
#define MM 450      // FINEMATCH_MAX_POINT
#define DD 256      // feat dim

// Probe whether bool inputs are packed uint8 (1B) or int32 (4B).
// (R5 evidence: masks are int32 on this harness; probe kept for robustness —
// cheap and branch-uniform.)
__device__ __forceinline__ bool probe_is_u8(const void* nb_mask_raw) {
    const unsigned int* w = (const unsigned int*)nb_mask_raw;
    bool u8 = false;
#pragma unroll
    for (int q = 0; q < 16; ++q) u8 |= (w[q] > 1u);
    return u8;
}

__device__ __forceinline__ int read_bool(const void* buf, int idx, bool is_u8) {
    if (is_u8) return ((const unsigned char*)buf)[idx] != 0;
    return ((const int*)buf)[idx] != 0;
}

// ---------------------------------------------------------------------------
// Kernel A: per-proposal mask build + stable compaction.
// One block (256 thr) per proposal; thread owns 4 consecutive l values.
// ws_order[p*LL + r] = l of the r-th valid position (increasing l = stable);
// ws_n[p] = valid count.
// ---------------------------------------------------------------------------
__global__ __launch_bounds__(256) void n2p_compact(
    const void* __restrict__ nb_mask_raw,   // [NP,NB] bool
    const int*  __restrict__ seed_idx,      // [NP,NB] int32
    const void* __restrict__ knn_mask_raw,  // [NNODES,KK] bool
    int* __restrict__ ws_order,             // [NP,LL]
    int* __restrict__ ws_n)                 // [NP]
{
    const int p = blockIdx.x;
    const int t = threadIdx.x;
    const bool is_u8 = probe_is_u8(nb_mask_raw);

    __shared__ int s_node[NB];
    __shared__ int s_m[NB];
    __shared__ int s_scan[256];

    if (t < NB) {
        s_node[t] = seed_idx[p * NB + t];
        s_m[t]    = read_bool(nb_mask_raw, p * NB + t, is_u8);
    }
    __syncthreads();

    const int base = t * 4;
    int v[4];
    int cnt = 0;
#pragma unroll
    for (int q = 0; q < 4; ++q) {
        const int l  = base + q;
        const int nb = l >> 6;
        const int k  = l & 63;
        const int valid = s_m[nb] && read_bool(knn_mask_raw, s_node[nb] * KK + k, is_u8);
        v[q] = valid;
        cnt += valid;
    }

    // Hillis-Steele inclusive scan over 256 per-thread counts.
    s_scan[t] = cnt;
    __syncthreads();
    int val = cnt;
    for (int off = 1; off < 256; off <<= 1) {
        int other = (t >= off) ? s_scan[t - off] : 0;
        __syncthreads();
        val += other;
        s_scan[t] = val;
        __syncthreads();
    }

    if (t == 255) ws_n[p] = val;

    int r = val - cnt;  // exclusive prefix = starting rank
#pragma unroll
    for (int q = 0; q < 4; ++q) {
        if (v[q]) ws_order[p * LL + (r++)] = base + q;
    }
}

// ---------------------------------------------------------------------------
// Kernel B: one wave (64 lanes) per output row (p,i). f32 in, f32 out.
// 64 lanes x float4 = one 1024B feat row, coalesced read + write.
// Resample index in EXACT integer arithmetic: j = (i*n)/450. i*n < 2^24 so
// this coincides with every multiply-first float variant, and resolves the
// ~1000 razor-edge pairs (i*n ≡ 0 mod 450) deterministically to m — which is
// what the comparison reference produces (R6 post-mortem: frac-first f32/f64
// each leave their own razor-pair residue, 17 / 90 wrong rows).
// ---------------------------------------------------------------------------
__global__ __launch_bounds__(256) void n2p_gather(
    const int*   __restrict__ seed_idx,  // [NP,NB]
    const float* __restrict__ knn_pts,   // [NNODES,KK,3]
    const int*   __restrict__ knn_idx,   // [NNODES,KK]
    const float* __restrict__ feats,     // [NPTS,DD]
    const int*   __restrict__ ws_order,  // [NP,LL]
    const int*   __restrict__ ws_n,      // [NP]
    float* __restrict__ out_pts,         // [NP,MM,3]
    float* __restrict__ out_feats,       // [NP,MM,DD]
    float* __restrict__ out_mask)        // [NP,MM]
{
    const int p    = blockIdx.x;
    const int wave = threadIdx.x >> 6;
    const int lane = threadIdx.x & 63;
    const int i    = blockIdx.y * 4 + wave;
    if (i >= MM) return;

    const int n     = ws_n[p];
    const int n_eff = (n < MM) ? n : MM;
    const size_t row = (size_t)p * MM + i;

    if (i < n_eff) {
        int j;
        if (n > MM) {
            j = (i * n) / MM;   // exact floor(i*n/450); i*n <= 459776 < 2^31
        } else {
            j = i;
        }
        const int l    = ws_order[p * LL + j];
        const int nb   = l >> 6;
        const int k    = l & 63;
        const int node = seed_idx[p * NB + nb];
        const int gk   = node * KK + k;
        const int idx  = knn_idx[gk];

        const float4 f = reinterpret_cast<const float4*>(feats + (size_t)idx * DD)[lane];
        reinterpret_cast<float4*>(out_feats + row * DD)[lane] = f;

        if (lane < 3)  out_pts[row * 3 + lane] = knn_pts[(size_t)gk * 3 + lane];
        if (lane == 0) out_mask[row] = 1.0f;
    } else {
        const float4 z = make_float4(0.f, 0.f, 0.f, 0.f);
        reinterpret_cast<float4*>(out_feats + row * DD)[lane] = z;
        if (lane < 3)  out_pts[row * 3 + lane] = 0.0f;
        if (lane == 0) out_mask[row] = 0.0f;
    }
}

extern "C" void kernel_launch(void* const* d_in, const int* in_sizes, int n_in,
                              void* d_out, int out_size, void* d_ws, size_t ws_size,
                              hipStream_t stream) {
    const void*  nb_mask  = d_in[0];                // [128,16] bool (u8 or i32, probed)
    const int*   seed_idx = (const int*)d_in[1];    // [128,16]
    const void*  knn_mask = d_in[2];                // [512,64] bool
    const float* knn_pts  = (const float*)d_in[3];  // [512,64,3] f32
    const int*   knn_idx  = (const int*)d_in[4];    // [512,64]
    const float* feats    = (const float*)d_in[5];  // [20000,256] f32

    float* out_pts   = (float*)d_out;                     // [128,450,3]
    float* out_feats = out_pts + (size_t)NP * MM * 3;     // [128,450,256]
    float* out_mask  = out_feats + (size_t)NP * MM * DD;  // [128,450]

    int* ws_n     = (int*)d_ws;   // [128]
    int* ws_order = ws_n + NP;    // [128,1024]

    n2p_compact<<<dim3(NP), dim3(256), 0, stream>>>(
        nb_mask, seed_idx, knn_mask, ws_order, ws_n);

    n2p_gather<<<dim3(NP, (MM + 3) / 4), dim3(256), 0, stream>>>(
        seed_idx, knn_pts, knn_idx, feats, ws_order, ws_n,
        out_pts, out_feats, out_mask);
}

// Round 8
// 104.612 us; speedup vs baseline: 1.0580x; 1.0580x over previous
//
#include <hip/hip_runtime.h>

#define NP 128      // proposals
#define NB 16       // neighbors per proposal
#define KK 64       // knn per node
#define LL 1024     // NB*KK
#define MM 450      // FINEMATCH_MAX_POINT
#define DD 256      // feat dim
#define CHUNKS 8    // row-chunks per proposal
#define ROWS 57     // ceil(MM / CHUNKS)

// Probe whether bool inputs are packed uint8 (1B) or int32 (4B).
// (R5/R7 evidence: int32 on this harness; probe kept — cheap, branch-uniform.)
__device__ __forceinline__ bool probe_is_u8(const void* nb_mask_raw) {
    const unsigned int* w = (const unsigned int*)nb_mask_raw;
    bool u8 = false;
#pragma unroll
    for (int q = 0; q < 16; ++q) u8 |= (w[q] > 1u);
    return u8;
}

__device__ __forceinline__ int read_bool(const void* buf, int idx, bool is_u8) {
    if (is_u8) return ((const unsigned char*)buf)[idx] != 0;
    return ((const int*)buf)[idx] != 0;
}

// ---------------------------------------------------------------------------
// Fused kernel: block (p, chunk) does compaction (ballot-based, 2 barriers,
// all in LDS) then streams its 57 output rows as float4 load->store.
//
// Compaction layout: wave wv covers l in [wv*256, wv*256+256), q-major:
//   l = wv*256 + q*64 + lane  ->  neighbor nb = wv*4+q (wave-uniform per q),
//   k = lane. knn_mask loads are perfectly coalesced; rank via ballot+popc.
// Order by (wave, q, lane) == order by l == stable compaction order.
// ---------------------------------------------------------------------------
__global__ __launch_bounds__(256) void n2p_fused(
    const void*  __restrict__ nb_mask_raw,   // [NP,NB] bool
    const int*   __restrict__ seed_idx,      // [NP,NB] int32
    const void*  __restrict__ knn_mask_raw,  // [NNODES,KK] bool
    const float* __restrict__ knn_pts,       // [NNODES,KK,3]
    const int*   __restrict__ knn_idx,       // [NNODES,KK]
    const float* __restrict__ feats,         // [NPTS,DD]
    float* __restrict__ out_pts,             // [NP,MM,3]
    float* __restrict__ out_feats,           // [NP,MM,DD]
    float* __restrict__ out_mask)            // [NP,MM]
{
    const int p     = blockIdx.x;
    const int chunk = blockIdx.y;
    const int t     = threadIdx.x;
    const int wv    = t >> 6;
    const int ln    = t & 63;

    __shared__ int s_node[NB];
    __shared__ int s_order[LL];   // valid l's, in order
    __shared__ int s_wsum[4];     // per-wave valid counts
    __shared__ int s_src[ROWS];   // per-row gk (node*KK+k), -1 => zero row
    __shared__ int s_fidx[ROWS];  // per-row feat index

    const bool is_u8 = probe_is_u8(nb_mask_raw);

    if (t < NB) s_node[t] = seed_idx[p * NB + t];
    __syncthreads();

    // ---- compaction ----
    int v[4];
#pragma unroll
    for (int q = 0; q < 4; ++q) {
        const int nbi  = wv * 4 + q;               // wave-uniform
        const int node = s_node[nbi];
        const int m_nb = read_bool(nb_mask_raw, p * NB + nbi, is_u8);
        const int m_kn = read_bool(knn_mask_raw, node * KK + ln, is_u8);
        v[q] = m_nb && m_kn;
    }
    const unsigned long long lt = (1ULL << ln) - 1ULL;  // lanes below me
    int my_rank[4];
    int wtot = 0;
#pragma unroll
    for (int q = 0; q < 4; ++q) {
        const unsigned long long b = __ballot(v[q] != 0);
        my_rank[q] = wtot + __popcll(b & lt);
        wtot += __popcll(b);
    }
    if (ln == 0) s_wsum[wv] = wtot;
    __syncthreads();

    int wave_off = 0;
    for (int w2 = 0; w2 < wv; ++w2) wave_off += s_wsum[w2];
    const int n_total = s_wsum[0] + s_wsum[1] + s_wsum[2] + s_wsum[3];
#pragma unroll
    for (int q = 0; q < 4; ++q) {
        if (v[q]) s_order[wave_off + my_rank[q]] = wv * 256 + q * 64 + ln;
    }
    __syncthreads();

    // ---- per-row index precompute + pts/mask writes (hoists the dependent
    //      chain out of the streaming loop) ----
    const int row0  = chunk * ROWS;
    const int nrows = (MM - row0 < ROWS) ? (MM - row0) : ROWS;
    const int n_eff = (n_total < MM) ? n_total : MM;

    if (t < nrows) {
        const int i = row0 + t;
        int src = -1, fidx = -1;
        if (i < n_eff) {
            // exact floor(i*n/450); i*n <= 459776 (R6: multiply-first is the
            // bit-exact contract vs the comparison reference)
            const int j = (n_total > MM) ? (int)((unsigned)(i * n_total) / (unsigned)MM)
                                         : i;
            const int l    = s_order[j];
            const int node = s_node[l >> 6];
            src  = node * KK + (l & 63);
            fidx = knn_idx[src];
        }
        s_src[t]  = src;
        s_fidx[t] = fidx;

        const size_t row = (size_t)p * MM + i;
        if (src >= 0) {
            out_pts[row * 3 + 0] = knn_pts[(size_t)src * 3 + 0];
            out_pts[row * 3 + 1] = knn_pts[(size_t)src * 3 + 1];
            out_pts[row * 3 + 2] = knn_pts[(size_t)src * 3 + 2];
            out_mask[row] = 1.0f;
        } else {
            out_pts[row * 3 + 0] = 0.0f;
            out_pts[row * 3 + 1] = 0.0f;
            out_pts[row * 3 + 2] = 0.0f;
            out_mask[row] = 0.0f;
        }
    }
    __syncthreads();

    // ---- streaming feat copy: one wave per row, 64 lanes x float4 = 1KB ----
    for (int r = wv; r < nrows; r += 4) {
        const size_t row = (size_t)p * MM + (row0 + r);
        const int fidx = s_fidx[r];                 // wave-uniform LDS read
        float4 f = make_float4(0.f, 0.f, 0.f, 0.f);
        if (fidx >= 0)
            f = reinterpret_cast<const float4*>(feats + (size_t)fidx * DD)[ln];
        reinterpret_cast<float4*>(out_feats + row * DD)[ln] = f;
    }
}

extern "C" void kernel_launch(void* const* d_in, const int* in_sizes, int n_in,
                              void* d_out, int out_size, void* d_ws, size_t ws_size,
                              hipStream_t stream) {
    const void*  nb_mask  = d_in[0];                // [128,16] bool (probed layout)
    const int*   seed_idx = (const int*)d_in[1];    // [128,16]
    const void*  knn_mask = d_in[2];                // [512,64] bool
    const float* knn_pts  = (const float*)d_in[3];  // [512,64,3] f32
    const int*   knn_idx  = (const int*)d_in[4];    // [512,64]
    const float* feats    = (const float*)d_in[5];  // [20000,256] f32

    float* out_pts   = (float*)d_out;                     // [128,450,3]
    float* out_feats = out_pts + (size_t)NP * MM * 3;     // [128,450,256]
    float* out_mask  = out_feats + (size_t)NP * MM * DD;  // [128,450]

    n2p_fused<<<dim3(NP, CHUNKS), dim3(256), 0, stream>>>(
        nb_mask, seed_idx, knn_mask, knn_pts, knn_idx, feats,
        out_pts, out_feats, out_mask);
}

// Round 9
// 102.290 us; speedup vs baseline: 1.0820x; 1.0227x over previous
//
#include <hip/hip_runtime.h>

#define NP 128      // proposals
#define NB 16       // neighbors per proposal
#define KK 64       // knn per node
#define LL 1024     // NB*KK
#define MM 450      // FINEMATCH_MAX_POINT
#define DD 256      // feat dim
#define CHUNKS 8    // row-chunks per proposal
#define ROWS 57     // ceil(MM / CHUNKS)

typedef float f32x4 __attribute__((ext_vector_type(4)));

// Probe whether bool inputs are packed uint8 (1B) or int32 (4B).
// (R5/R7 evidence: int32 on this harness; probe kept — cheap, branch-uniform.)
__device__ __forceinline__ bool probe_is_u8(const void* nb_mask_raw) {
    const unsigned int* w = (const unsigned int*)nb_mask_raw;
    bool u8 = false;
#pragma unroll
    for (int q = 0; q < 16; ++q) u8 |= (w[q] > 1u);
    return u8;
}

__device__ __forceinline__ int read_bool(const void* buf, int idx, bool is_u8) {
    if (is_u8) return ((const unsigned char*)buf)[idx] != 0;
    return ((const int*)buf)[idx] != 0;
}

// ---------------------------------------------------------------------------
// Fused kernel: block (p, chunk) does ballot-based compaction in LDS, then
// streams its 57 output rows. Feat stores are NONTEMPORAL (60 MB stream,
// never re-read) so the 20.5 MB feat table keeps the per-XCD L2. Streaming
// loop keeps 2 rows in flight per wave (both loads issued before stores).
// ---------------------------------------------------------------------------
__global__ __launch_bounds__(256) void n2p_fused(
    const void*  __restrict__ nb_mask_raw,   // [NP,NB] bool
    const int*   __restrict__ seed_idx,      // [NP,NB] int32
    const void*  __restrict__ knn_mask_raw,  // [NNODES,KK] bool
    const float* __restrict__ knn_pts,       // [NNODES,KK,3]
    const int*   __restrict__ knn_idx,       // [NNODES,KK]
    const float* __restrict__ feats,         // [NPTS,DD]
    float* __restrict__ out_pts,             // [NP,MM,3]
    float* __restrict__ out_feats,           // [NP,MM,DD]
    float* __restrict__ out_mask)            // [NP,MM]
{
    const int p     = blockIdx.x;
    const int chunk = blockIdx.y;
    const int t     = threadIdx.x;
    const int wv    = t >> 6;
    const int ln    = t & 63;

    __shared__ int s_node[NB];
    __shared__ int s_order[LL];   // valid l's, in order
    __shared__ int s_wsum[4];     // per-wave valid counts
    __shared__ int s_fidx[ROWS];  // per-row feat index (-1 => zero row)

    const bool is_u8 = probe_is_u8(nb_mask_raw);

    if (t < NB) s_node[t] = seed_idx[p * NB + t];
    __syncthreads();

    // ---- compaction: l = wv*256 + q*64 + ln; rank via ballot+popc ----
    int v[4];
#pragma unroll
    for (int q = 0; q < 4; ++q) {
        const int nbi  = wv * 4 + q;               // wave-uniform
        const int node = s_node[nbi];
        const int m_nb = read_bool(nb_mask_raw, p * NB + nbi, is_u8);
        const int m_kn = read_bool(knn_mask_raw, node * KK + ln, is_u8);
        v[q] = m_nb && m_kn;
    }
    const unsigned long long lt = (1ULL << ln) - 1ULL;
    int my_rank[4];
    int wtot = 0;
#pragma unroll
    for (int q = 0; q < 4; ++q) {
        const unsigned long long b = __ballot(v[q] != 0);
        my_rank[q] = wtot + __popcll(b & lt);
        wtot += __popcll(b);
    }
    if (ln == 0) s_wsum[wv] = wtot;
    __syncthreads();

    int wave_off = 0;
    for (int w2 = 0; w2 < wv; ++w2) wave_off += s_wsum[w2];
    const int n_total = s_wsum[0] + s_wsum[1] + s_wsum[2] + s_wsum[3];
#pragma unroll
    for (int q = 0; q < 4; ++q) {
        if (v[q]) s_order[wave_off + my_rank[q]] = wv * 256 + q * 64 + ln;
    }
    __syncthreads();

    // ---- per-row index precompute + pts/mask writes ----
    const int row0  = chunk * ROWS;
    const int nrows = (MM - row0 < ROWS) ? (MM - row0) : ROWS;
    const int n_eff = (n_total < MM) ? n_total : MM;

    if (t < nrows) {
        const int i = row0 + t;
        int src = -1, fidx = -1;
        if (i < n_eff) {
            // exact floor(i*n/450) — bit-exact contract vs np reference (R6)
            const int j = (n_total > MM) ? (int)((unsigned)(i * n_total) / (unsigned)MM)
                                         : i;
            const int l    = s_order[j];
            const int node = s_node[l >> 6];
            src  = node * KK + (l & 63);
            fidx = knn_idx[src];
        }
        s_fidx[t] = fidx;

        const size_t row = (size_t)p * MM + i;
        if (src >= 0) {
            out_pts[row * 3 + 0] = knn_pts[(size_t)src * 3 + 0];
            out_pts[row * 3 + 1] = knn_pts[(size_t)src * 3 + 1];
            out_pts[row * 3 + 2] = knn_pts[(size_t)src * 3 + 2];
            out_mask[row] = 1.0f;
        } else {
            out_pts[row * 3 + 0] = 0.0f;
            out_pts[row * 3 + 1] = 0.0f;
            out_pts[row * 3 + 2] = 0.0f;
            out_mask[row] = 0.0f;
        }
    }
    __syncthreads();

    // ---- streaming feat copy: wave per row, 2 rows in flight, nt stores ----
    const float* base_out = out_feats + ((size_t)p * MM + row0) * DD;
    int r = wv;
    for (; r + 4 < nrows; r += 8) {
        const int f0 = s_fidx[r];
        const int f1 = s_fidx[r + 4];
        const int c0 = (f0 >= 0) ? f0 : 0;   // branchless: clamp + select
        const int c1 = (f1 >= 0) ? f1 : 0;
        f32x4 a = reinterpret_cast<const f32x4*>(feats + (size_t)c0 * DD)[ln];
        f32x4 b = reinterpret_cast<const f32x4*>(feats + (size_t)c1 * DD)[ln];
        if (f0 < 0) a = (f32x4)(0.f);
        if (f1 < 0) b = (f32x4)(0.f);
        __builtin_nontemporal_store(a, (f32x4*)(base_out + (size_t)r * DD) + ln);
        __builtin_nontemporal_store(b, (f32x4*)(base_out + (size_t)(r + 4) * DD) + ln);
    }
    if (r < nrows) {
        const int f0 = s_fidx[r];
        const int c0 = (f0 >= 0) ? f0 : 0;
        f32x4 a = reinterpret_cast<const f32x4*>(feats + (size_t)c0 * DD)[ln];
        if (f0 < 0) a = (f32x4)(0.f);
        __builtin_nontemporal_store(a, (f32x4*)(base_out + (size_t)r * DD) + ln);
    }
}

extern "C" void kernel_launch(void* const* d_in, const int* in_sizes, int n_in,
                              void* d_out, int out_size, void* d_ws, size_t ws_size,
                              hipStream_t stream) {
    const void*  nb_mask  = d_in[0];                // [128,16] bool (probed layout)
    const int*   seed_idx = (const int*)d_in[1];    // [128,16]
    const void*  knn_mask = d_in[2];                // [512,64] bool
    const float* knn_pts  = (const float*)d_in[3];  // [512,64,3] f32
    const int*   knn_idx  = (const int*)d_in[4];    // [512,64]
    const float* feats    = (const float*)d_in[5];  // [20000,256] f32

    float* out_pts   = (float*)d_out;                     // [128,450,3]
    float* out_feats = out_pts + (size_t)NP * MM * 3;     // [128,450,256]
    float* out_mask  = out_feats + (size_t)NP * MM * DD;  // [128,450]

    n2p_fused<<<dim3(NP, CHUNKS), dim3(256), 0, stream>>>(
        nb_mask, seed_idx, knn_mask, knn_pts, knn_idx, feats,
        out_pts, out_feats, out_mask);
}